// Round 3
// baseline (197.677 us; speedup 1.0000x reference)
//
#include <hip/hip_runtime.h>
#include <hip/hip_bf16.h>
#include <stdint.h>

// MoE experts: E=8, T=2048, H=1024, I=2048, contiguous token groups.
// up = h@w1_e ; up_r = h@w3_e ; gated = silu(up)*up_r ; out = gated@w2_e
// bf16 MFMA compute, fp32 accumulate. Weights converted fp32->bf16 on the fly.
//
// Round-3: fix expert->XCD pinning (nt-major wg order + bijective chunk
// swizzle => weights of every expert spread across all 8 XCDs, mt-neighbors
// share a B-panel within one XCD's L2). BM=128 halves weight re-reads.
// 8-wave blocks, B staged via 8B-subslot XOR layout (conflict-lite).

#define NE 8
#define NT 2048
#define NH 1024
#define NI 2048

typedef __attribute__((ext_vector_type(8))) short bh8;      // 8 bf16
typedef __attribute__((ext_vector_type(4))) short bh4;      // 4 bf16
typedef __attribute__((ext_vector_type(4))) float f32x4;
typedef __attribute__((ext_vector_type(2))) float f32x2;
typedef __attribute__((ext_vector_type(4))) float float4v;

static __device__ __forceinline__ unsigned short f2bf(float f) {
  __hip_bfloat16 h = __float2bfloat16(f);   // RNE
  return *reinterpret_cast<unsigned short*>(&h);
}

// ---- hiddens fp32 -> bf16 (ws) ----
__global__ __launch_bounds__(256)
void cvt_h_kernel(const float* __restrict__ x, unsigned short* __restrict__ y) {
  int i = blockIdx.x * 256 + threadIdx.x;           // one bh8 per thread
  const float4v* xv = reinterpret_cast<const float4v*>(x);
  float4v a = xv[2 * i], b = xv[2 * i + 1];
  union { bh8 v; unsigned short u[8]; } o;
  o.u[0] = f2bf(a[0]); o.u[1] = f2bf(a[1]); o.u[2] = f2bf(a[2]); o.u[3] = f2bf(a[3]);
  o.u[4] = f2bf(b[0]); o.u[5] = f2bf(b[1]); o.u[6] = f2bf(b[2]); o.u[7] = f2bf(b[3]);
  reinterpret_cast<bh8*>(y)[i] = o.v;
}

// LDS layouts:
//  A: [row 128][k 32] bf16, 4 x 16B slots/row, slot' = slot ^ ((row>>1)&3),
//     staged by global_load_lds with pre-swizzled global source.
//  B: [n 128][k 32] bf16, 8 x 8B subslots/row (subslot s holds k=4s..4s+3),
//     subslot' = s ^ (n&7). Wave w writes subslot w (k rows 4w..4w+3).
//     Fragment read = paired ds_read_b64 (subslots 2g, 2g+1, g = lane>>4).

// ============ GEMM1: fused h@w1 / h@w3 + silu-gate -> gated bf16 ============
// BM=128 BN=128 BK=32, 8 waves (2x4), double-buffered LDS.
__global__ __launch_bounds__(512, 2)
void moe_gemm1(const unsigned short* __restrict__ hb,   // [T][H] bf16
               const float* __restrict__ w1,            // [E][H][I]
               const float* __restrict__ w3,            // [E][H][I]
               const int* __restrict__ bsz,
               unsigned short* __restrict__ gated) {    // [T][I] bf16
  const int NWG = 2048;                        // nt(16) x e(8) x mt(16)
  const int wg = (blockIdx.x & 7) * (NWG >> 3) + (blockIdx.x >> 3);
  const int mt = wg & 15;                      // minor: same (nt,e) panel
  const int e = (wg >> 4) & 7;                 // mid: experts spread per chunk
  const int nt = wg >> 7;                      // major: 2 nt per XCD chunk

  int off = 0;
#pragma unroll
  for (int j = 0; j < NE; ++j) { int v = bsz[j]; off += (j < e) ? v : 0; }
  const int te = bsz[e];
  if (mt * 128 >= te) return;

  const int tid = threadIdx.x;
  const int l = tid & 63, w = tid >> 6;
  const int wr = w >> 2, wc = w & 3;           // wave tile 64m x 32n

  __shared__ __align__(16) unsigned short As[2][128 * 32];   // 2 x 8KB
  __shared__ __align__(16) unsigned short B1s[2][128 * 32];  // 2 x 8KB
  __shared__ __align__(16) unsigned short B3s[2][128 * 32];  // 2 x 8KB

  const int row0 = off + mt * 128;
  const int col0 = nt * 128;

  // A staging: wave w stages rows 16w..16w+15; lane l: row 16w+(l>>2), dest
  // linear; source k-chunk pre-swizzled (l&3)^((l>>3)&3).
  int gr = row0 + w * 16 + (l >> 2); if (gr > NT - 1) gr = NT - 1;
  const int gslA = ((l & 3) ^ ((l >> 3) & 3)) * 8;
  const unsigned short* agA = hb + (size_t)gr * NH + gslA;

  // B staging: lane covers cols n0=2l, n1=2l+1; wave w covers k rows 4w..4w+3.
  const int n0 = 2 * l, n1 = 2 * l + 1;
  const float* w1p = w1 + (size_t)e * NH * NI + (size_t)(4 * w) * NI + (col0 + n0);
  const float* w3p = w3 + (size_t)e * NH * NI + (size_t)(4 * w) * NI + (col0 + n0);
  const int wb0 = n0 * 32 + ((w ^ (n0 & 7)) << 2);   // shorts
  const int wb1 = n1 * 32 + ((w ^ (n1 & 7)) << 2);

  // fragment reads
  const int arow = wr * 64 + (l & 15);
  const int fslA = ((l >> 4) ^ ((l >> 1) & 3)) << 3;
  const int g2 = (l >> 4) << 1;
  const int nb0 = wc * 32 + (l & 15);

  f32x4 acc1[4][2] = {};
  f32x4 acc3[4][2] = {};
  f32x2 rb1[4], rb3[4];

  auto issueA = [&](int k0, int b) {
    __builtin_amdgcn_global_load_lds(
        (const __attribute__((address_space(1))) void*)(agA + k0),
        (__attribute__((address_space(3))) void*)(&As[b][0] + w * 512), 16, 0, 0);
  };
  auto loadB = [&](int k0) {
#pragma unroll
    for (int j = 0; j < 4; ++j) rb1[j] = *(const f32x2*)(w1p + (size_t)(k0 + j) * NI);
#pragma unroll
    for (int j = 0; j < 4; ++j) rb3[j] = *(const f32x2*)(w3p + (size_t)(k0 + j) * NI);
  };
  auto writeB = [&](int b) {
    bh4 q0, q1, r0, r1;
#pragma unroll
    for (int j = 0; j < 4; ++j) {
      q0[j] = (short)f2bf(rb1[j][0]); q1[j] = (short)f2bf(rb1[j][1]);
      r0[j] = (short)f2bf(rb3[j][0]); r1[j] = (short)f2bf(rb3[j][1]);
    }
    *(bh4*)(&B1s[b][0] + wb0) = q0;
    *(bh4*)(&B1s[b][0] + wb1) = q1;
    *(bh4*)(&B3s[b][0] + wb0) = r0;
    *(bh4*)(&B3s[b][0] + wb1) = r1;
  };
  auto rdB = [&](const unsigned short* B, int nf) -> bh8 {
    const int n = nb0 + nf * 16;
    bh4 lo = *(const bh4*)(B + n * 32 + ((g2 ^ (n & 7)) << 2));
    bh4 hi = *(const bh4*)(B + n * 32 + (((g2 + 1) ^ (n & 7)) << 2));
    bh8 r;
    r[0] = lo[0]; r[1] = lo[1]; r[2] = lo[2]; r[3] = lo[3];
    r[4] = hi[0]; r[5] = hi[1]; r[6] = hi[2]; r[7] = hi[3];
    return r;
  };

  issueA(0, 0);
  loadB(0);
  writeB(0);
  __syncthreads();

  for (int t = 0; t < 32; ++t) {
    const int cb = t & 1, nb = cb ^ 1;
    if (t + 1 < 32) {                 // issue next-tile loads BEFORE compute
      issueA((t + 1) * 32, nb);
      loadB((t + 1) * 32);
    }
    bh8 af[4];
#pragma unroll
    for (int m = 0; m < 4; ++m)
      af[m] = *(const bh8*)(&As[cb][0] + (arow + m * 16) * 32 + fslA);
#pragma unroll
    for (int nf = 0; nf < 2; ++nf) {
      bh8 b1f = rdB(&B1s[cb][0], nf);
      bh8 b3f = rdB(&B3s[cb][0], nf);
#pragma unroll
      for (int m = 0; m < 4; ++m) {
        acc1[m][nf] = __builtin_amdgcn_mfma_f32_16x16x32_bf16(af[m], b1f, acc1[m][nf], 0, 0, 0);
        acc3[m][nf] = __builtin_amdgcn_mfma_f32_16x16x32_bf16(af[m], b3f, acc3[m][nf], 0, 0, 0);
      }
    }
    if (t + 1 < 32) writeB(nb);       // cvt + ds_write AFTER compute (T14)
    __syncthreads();
  }

  // epilogue: silu(acc1)*acc3 -> gated bf16, masked by ragged bound
#pragma unroll
  for (int m = 0; m < 4; ++m) {
#pragma unroll
    for (int r = 0; r < 4; ++r) {
      int trow = mt * 128 + wr * 64 + m * 16 + (l >> 4) * 4 + r;
      if (trow < te) {
        size_t base = (size_t)(off + trow) * NI + col0 + wc * 32 + (l & 15);
#pragma unroll
        for (int nf = 0; nf < 2; ++nf) {
          float u = acc1[m][nf][r];
          float g = acc3[m][nf][r];
          gated[base + nf * 16] = f2bf((u / (1.f + __expf(-u))) * g);
        }
      }
    }
  }
}

// ============ GEMM2: gated @ w2 -> out fp32 ============
// BM=128 BN=128 BK=32, 8 waves (2x4), double-buffered LDS. K=2048 (64 steps).
__global__ __launch_bounds__(512, 2)
void moe_gemm2(const unsigned short* __restrict__ gated,  // [T][I] bf16
               const float* __restrict__ w2,              // [E][I][H]
               const int* __restrict__ bsz,
               float* __restrict__ out) {                 // [T][H] fp32
  const int NWG = 1024;                        // nt(8) x e(8) x mt(16)
  const int wg = (blockIdx.x & 7) * (NWG >> 3) + (blockIdx.x >> 3);
  const int mt = wg & 15;
  const int e = (wg >> 4) & 7;
  const int nt = wg >> 7;

  int off = 0;
#pragma unroll
  for (int j = 0; j < NE; ++j) { int v = bsz[j]; off += (j < e) ? v : 0; }
  const int te = bsz[e];
  if (mt * 128 >= te) return;

  const int tid = threadIdx.x;
  const int l = tid & 63, w = tid >> 6;
  const int wr = w >> 2, wc = w & 3;

  __shared__ __align__(16) unsigned short As[2][128 * 32];  // 2 x 8KB
  __shared__ __align__(16) unsigned short Bs[2][128 * 32];  // 2 x 8KB

  const int row0 = off + mt * 128;
  const int col0 = nt * 128;

  int gr = row0 + w * 16 + (l >> 2); if (gr > NT - 1) gr = NT - 1;
  const int gslA = ((l & 3) ^ ((l >> 3) & 3)) * 8;
  const unsigned short* agA = gated + (size_t)gr * NI + gslA;

  const int n0 = 2 * l, n1 = 2 * l + 1;
  const float* w2p = w2 + (size_t)e * NI * NH + (size_t)(4 * w) * NH + (col0 + n0);
  const int wb0 = n0 * 32 + ((w ^ (n0 & 7)) << 2);
  const int wb1 = n1 * 32 + ((w ^ (n1 & 7)) << 2);

  const int arow = wr * 64 + (l & 15);
  const int fslA = ((l >> 4) ^ ((l >> 1) & 3)) << 3;
  const int g2 = (l >> 4) << 1;
  const int nb0 = wc * 32 + (l & 15);

  f32x4 acc[4][2] = {};
  f32x2 rb[4];

  auto issueA = [&](int k0, int b) {
    __builtin_amdgcn_global_load_lds(
        (const __attribute__((address_space(1))) void*)(agA + k0),
        (__attribute__((address_space(3))) void*)(&As[b][0] + w * 512), 16, 0, 0);
  };
  auto loadB = [&](int k0) {
#pragma unroll
    for (int j = 0; j < 4; ++j) rb[j] = *(const f32x2*)(w2p + (size_t)(k0 + j) * NH);
  };
  auto writeB = [&](int b) {
    bh4 q0, q1;
#pragma unroll
    for (int j = 0; j < 4; ++j) {
      q0[j] = (short)f2bf(rb[j][0]); q1[j] = (short)f2bf(rb[j][1]);
    }
    *(bh4*)(&Bs[b][0] + wb0) = q0;
    *(bh4*)(&Bs[b][0] + wb1) = q1;
  };
  auto rdB = [&](const unsigned short* B, int nf) -> bh8 {
    const int n = nb0 + nf * 16;
    bh4 lo = *(const bh4*)(B + n * 32 + ((g2 ^ (n & 7)) << 2));
    bh4 hi = *(const bh4*)(B + n * 32 + (((g2 + 1) ^ (n & 7)) << 2));
    bh8 r;
    r[0] = lo[0]; r[1] = lo[1]; r[2] = lo[2]; r[3] = lo[3];
    r[4] = hi[0]; r[5] = hi[1]; r[6] = hi[2]; r[7] = hi[3];
    return r;
  };

  issueA(0, 0);
  loadB(0);
  writeB(0);
  __syncthreads();

  for (int t = 0; t < 64; ++t) {
    const int cb = t & 1, nb = cb ^ 1;
    if (t + 1 < 64) {
      issueA((t + 1) * 32, nb);
      loadB((t + 1) * 32);
    }
    bh8 af[4];
#pragma unroll
    for (int m = 0; m < 4; ++m)
      af[m] = *(const bh8*)(&As[cb][0] + (arow + m * 16) * 32 + fslA);
#pragma unroll
    for (int nf = 0; nf < 2; ++nf) {
      bh8 bf = rdB(&Bs[cb][0], nf);
#pragma unroll
      for (int m = 0; m < 4; ++m)
        acc[m][nf] = __builtin_amdgcn_mfma_f32_16x16x32_bf16(af[m], bf, acc[m][nf], 0, 0, 0);
    }
    if (t + 1 < 64) writeB(nb);
    __syncthreads();
  }

#pragma unroll
  for (int m = 0; m < 4; ++m) {
#pragma unroll
    for (int r = 0; r < 4; ++r) {
      int trow = mt * 128 + wr * 64 + m * 16 + (l >> 4) * 4 + r;
      if (trow < te) {
        size_t base = (size_t)(off + trow) * NH + col0 + wc * 32 + (l & 15);
#pragma unroll
        for (int nf = 0; nf < 2; ++nf)
          out[base + nf * 16] = acc[m][nf][r];
      }
    }
  }
}

extern "C" void kernel_launch(void* const* d_in, const int* in_sizes, int n_in,
                              void* d_out, int out_size, void* d_ws, size_t ws_size,
                              hipStream_t stream) {
  const float* hiddens = (const float*)d_in[0];
  const float* w1 = (const float*)d_in[1];
  const float* w2 = (const float*)d_in[2];
  const float* w3 = (const float*)d_in[3];
  const int* bsz = (const int*)d_in[4];
  float* out = (float*)d_out;

  // ws: [0, 4MB) hiddens bf16 ; [4MB, 12MB) gated bf16
  unsigned short* hb = (unsigned short*)d_ws;
  unsigned short* gated = hb + (size_t)NT * NH;

  cvt_h_kernel<<<dim3(NT * NH / 8 / 256), dim3(256), 0, stream>>>(hiddens, hb);
  moe_gemm1<<<dim3(2048), dim3(512), 0, stream>>>(hb, w1, w3, bsz, gated);
  moe_gemm2<<<dim3(1024), dim3(512), 0, stream>>>(gated, w2, bsz, out);
}

// Round 4
// 135.001 us; speedup vs baseline: 1.4643x; 1.4643x over previous
//
#include <hip/hip_runtime.h>
#include <hip/hip_bf16.h>
#include <stdint.h>

// MoE experts: E=8, T=2048, H=1024, I=2048, contiguous token groups.
// up = h@w1_e ; up_r = h@w3_e ; gated = silu(up)*up_r ; out = gated@w2_e
// bf16 MFMA compute, fp32 accumulate, weights cvt'd fp32->bf16 on the fly.
//
// Round-4: kill the per-K-step vmcnt(0) drain. All staging is reg-staged
// (global->reg->cvt->ds_write), barriers are raw lgkmcnt(0)+s_barrier (no
// vmem drain), prefetch distance 2 with NAMED register sets -> ~18 loads
// per thread stay in flight across barriers (T4 counted-vmcnt pattern).
// B LDS layout upgraded to 16B slots (slot ^ ((n>>1)&3)) -> single
// ds_read_b128 per fragment.

#define NE 8
#define NT 2048
#define NH 1024
#define NI 2048

typedef __attribute__((ext_vector_type(8))) short bh8;      // 8 bf16
typedef __attribute__((ext_vector_type(4))) short bh4;      // 4 bf16
typedef __attribute__((ext_vector_type(4))) float f32x4;
typedef __attribute__((ext_vector_type(2))) float f32x2;
typedef __attribute__((ext_vector_type(4))) float float4v;

#define BARRIER() asm volatile("s_waitcnt lgkmcnt(0)\n\ts_barrier" ::: "memory")

static __device__ __forceinline__ unsigned short f2bf(float f) {
  __hip_bfloat16 h = __float2bfloat16(f);   // RNE
  return *reinterpret_cast<unsigned short*>(&h);
}

// ---- hiddens fp32 -> bf16 (ws) ----
__global__ __launch_bounds__(256)
void cvt_h_kernel(const float* __restrict__ x, unsigned short* __restrict__ y) {
  int i = blockIdx.x * 256 + threadIdx.x;           // one bh8 per thread
  const float4v* xv = reinterpret_cast<const float4v*>(x);
  float4v a = xv[2 * i], b = xv[2 * i + 1];
  union { bh8 v; unsigned short u[8]; } o;
  o.u[0] = f2bf(a[0]); o.u[1] = f2bf(a[1]); o.u[2] = f2bf(a[2]); o.u[3] = f2bf(a[3]);
  o.u[4] = f2bf(b[0]); o.u[5] = f2bf(b[1]); o.u[6] = f2bf(b[2]); o.u[7] = f2bf(b[3]);
  reinterpret_cast<bh8*>(y)[i] = o.v;
}

// LDS layouts (both A and B): [row 128][k 32] bf16, 4 x 16B slots per row,
// slot' = slot ^ ((row>>1)&3). Fragment read = single ds_read_b128 at
// slot (l>>4) ^ perm(row). A written as full b128 per thread; B written as
// two b64 halves (wave w holds k-quad 4w..4w+3 = half of slot w>>1).

// ============ GEMM1: fused h@w1 / h@w3 + silu-gate -> gated bf16 ============
// BM=128 BN=128 BK=32, 8 waves (2x4), double-buffered LDS, dist-2 prefetch.
__global__ __launch_bounds__(512, 2)
void moe_gemm1(const unsigned short* __restrict__ hb,   // [T][H] bf16
               const float* __restrict__ w1,            // [E][H][I]
               const float* __restrict__ w3,            // [E][H][I]
               const int* __restrict__ bsz,
               unsigned short* __restrict__ gated) {    // [T][I] bf16
  const int NWG = 2048;                        // nt(16) x e(8) x mt(16)
  const int wg = (blockIdx.x & 7) * (NWG >> 3) + (blockIdx.x >> 3);
  const int mt = wg & 15;                      // minor: same (nt,e) B-panel
  const int e = (wg >> 4) & 7;                 // experts spread within chunk
  const int nt = wg >> 7;                      // 2 nt per XCD chunk

  int off = 0;
#pragma unroll
  for (int j = 0; j < NE; ++j) { int v = bsz[j]; off += (j < e) ? v : 0; }
  const int te = bsz[e];
  if (mt * 128 >= te) return;

  const int tid = threadIdx.x;
  const int l = tid & 63, w = tid >> 6;
  const int wr = w >> 2, wc = w & 3;           // wave tile 64m x 32n

  __shared__ __align__(16) unsigned short As[2][128 * 32];   // 2 x 8KB
  __shared__ __align__(16) unsigned short B1s[2][128 * 32];  // 2 x 8KB
  __shared__ __align__(16) unsigned short B3s[2][128 * 32];  // 2 x 8KB

  const int row0 = off + mt * 128;
  const int col0 = nt * 128;

  // A: thread owns row tid>>2, slot tid&3 (bh8 global load, swizzled ds_write)
  int gr = row0 + (tid >> 2); if (gr > NT - 1) gr = NT - 1;
  const unsigned short* agA = hb + (size_t)gr * NH + (tid & 3) * 8;
  const int awo = (tid >> 2) * 32 + (((tid & 3) ^ ((tid >> 3) & 3)) * 8);

  // B: lane owns cols n0=2l, n0+1; wave w owns k-quad 4w..4w+3.
  const int n0 = 2 * l;
  const float* w1p = w1 + (size_t)e * NH * NI + (size_t)(4 * w) * NI + (col0 + n0);
  const float* w3p = w3 + (size_t)e * NH * NI + (size_t)(4 * w) * NI + (col0 + n0);
  const int bwo = n0 * 32 + (((w >> 1) ^ (l & 3)) * 8) + (w & 1) * 4;  // shorts

  // fragment read offsets
  const int arow = wr * 64 + (l & 15);
  const int fslA = ((l >> 4) ^ ((l >> 1) & 3)) * 8;
  const int nbase = wc * 32 + (l & 15);
  const int bsl = ((l >> 4) ^ ((nbase >> 1) & 3)) * 8;  // same for nf=0,1

  f32x4 acc1[4][2] = {};
  f32x4 acc3[4][2] = {};
  f32x2 rb1A[4], rb3A[4], rb1B[4], rb3B[4];
  bh8 rAA, rAB;

  auto issue = [&](int t, bh8& rA_, f32x2 (&rb1_)[4], f32x2 (&rb3_)[4]) {
    const int k0 = t * 32;
    rA_ = *(const bh8*)(agA + k0);
#pragma unroll
    for (int j = 0; j < 4; ++j) rb1_[j] = *(const f32x2*)(w1p + (size_t)(k0 + j) * NI);
#pragma unroll
    for (int j = 0; j < 4; ++j) rb3_[j] = *(const f32x2*)(w3p + (size_t)(k0 + j) * NI);
  };
  auto stage = [&](int b, bh8& rA_, f32x2 (&rb1_)[4], f32x2 (&rb3_)[4]) {
    *(bh8*)(&As[b][awo]) = rA_;
    bh4 q0, q1, r0, r1;
#pragma unroll
    for (int j = 0; j < 4; ++j) {
      q0[j] = (short)f2bf(rb1_[j][0]); q1[j] = (short)f2bf(rb1_[j][1]);
      r0[j] = (short)f2bf(rb3_[j][0]); r1[j] = (short)f2bf(rb3_[j][1]);
    }
    *(bh4*)(&B1s[b][bwo]) = q0;
    *(bh4*)(&B1s[b][bwo + 32]) = q1;
    *(bh4*)(&B3s[b][bwo]) = r0;
    *(bh4*)(&B3s[b][bwo + 32]) = r1;
  };
  auto mfma_step = [&](int b) {
    bh8 af[4];
#pragma unroll
    for (int m = 0; m < 4; ++m)
      af[m] = *(const bh8*)(&As[b][(arow + m * 16) * 32 + fslA]);
#pragma unroll
    for (int nf = 0; nf < 2; ++nf) {
      bh8 b1f = *(const bh8*)(&B1s[b][(nbase + nf * 16) * 32 + bsl]);
      bh8 b3f = *(const bh8*)(&B3s[b][(nbase + nf * 16) * 32 + bsl]);
#pragma unroll
      for (int m = 0; m < 4; ++m) {
        acc1[m][nf] = __builtin_amdgcn_mfma_f32_16x16x32_bf16(af[m], b1f, acc1[m][nf], 0, 0, 0);
        acc3[m][nf] = __builtin_amdgcn_mfma_f32_16x16x32_bf16(af[m], b3f, acc3[m][nf], 0, 0, 0);
      }
    }
  };

  // prologue: tiles 0 (set A) and 1 (set B) in flight; stage tile0 -> LDS0.
  issue(0, rAA, rb1A, rb3A);
  issue(1, rAB, rb1B, rb3B);
  stage(0, rAA, rb1A, rb3A);
  BARRIER();

#pragma unroll 1
  for (int u = 0; u < 16; ++u) {
    const int t0 = 2 * u;
    if (t0 + 2 < 32) issue(t0 + 2, rAA, rb1A, rb3A);   // even tile -> set A
    mfma_step(0);                                       // tile t0 (LDS0)
    stage(1, rAB, rb1B, rb3B);                          // tile t0+1 -> LDS1
    BARRIER();
    if (t0 + 3 < 32) issue(t0 + 3, rAB, rb1B, rb3B);   // odd tile -> set B
    mfma_step(1);                                       // tile t0+1 (LDS1)
    if (t0 + 2 < 32) stage(0, rAA, rb1A, rb3A);        // tile t0+2 -> LDS0
    BARRIER();
  }

  // epilogue: silu(acc1)*acc3 -> gated bf16, masked by ragged bound
#pragma unroll
  for (int m = 0; m < 4; ++m) {
#pragma unroll
    for (int r = 0; r < 4; ++r) {
      int trow = mt * 128 + wr * 64 + m * 16 + (l >> 4) * 4 + r;
      if (trow < te) {
        size_t base = (size_t)(off + trow) * NI + col0 + wc * 32 + (l & 15);
#pragma unroll
        for (int nf = 0; nf < 2; ++nf) {
          float u2 = acc1[m][nf][r];
          float g = acc3[m][nf][r];
          gated[base + nf * 16] = f2bf((u2 / (1.f + __expf(-u2))) * g);
        }
      }
    }
  }
}

// ============ GEMM2: gated @ w2 -> out fp32 ============
// BM=128 BN=128 BK=32, 8 waves, double-buffered LDS, dist-2 prefetch. 64 tiles.
__global__ __launch_bounds__(512, 2)
void moe_gemm2(const unsigned short* __restrict__ gated,  // [T][I] bf16
               const float* __restrict__ w2,              // [E][I][H]
               const int* __restrict__ bsz,
               float* __restrict__ out) {                 // [T][H] fp32
  const int NWG = 1024;                        // nt(8) x e(8) x mt(16)
  const int wg = (blockIdx.x & 7) * (NWG >> 3) + (blockIdx.x >> 3);
  const int mt = wg & 15;
  const int e = (wg >> 4) & 7;
  const int nt = wg >> 7;

  int off = 0;
#pragma unroll
  for (int j = 0; j < NE; ++j) { int v = bsz[j]; off += (j < e) ? v : 0; }
  const int te = bsz[e];
  if (mt * 128 >= te) return;

  const int tid = threadIdx.x;
  const int l = tid & 63, w = tid >> 6;
  const int wr = w >> 2, wc = w & 3;

  __shared__ __align__(16) unsigned short As[2][128 * 32];  // 2 x 8KB
  __shared__ __align__(16) unsigned short Bs[2][128 * 32];  // 2 x 8KB

  const int row0 = off + mt * 128;
  const int col0 = nt * 128;

  int gr = row0 + (tid >> 2); if (gr > NT - 1) gr = NT - 1;
  const unsigned short* agA = gated + (size_t)gr * NI + (tid & 3) * 8;
  const int awo = (tid >> 2) * 32 + (((tid & 3) ^ ((tid >> 3) & 3)) * 8);

  const int n0 = 2 * l;
  const float* w2p = w2 + (size_t)e * NI * NH + (size_t)(4 * w) * NH + (col0 + n0);
  const int bwo = n0 * 32 + (((w >> 1) ^ (l & 3)) * 8) + (w & 1) * 4;

  const int arow = wr * 64 + (l & 15);
  const int fslA = ((l >> 4) ^ ((l >> 1) & 3)) * 8;
  const int nbase = wc * 32 + (l & 15);
  const int bsl = ((l >> 4) ^ ((nbase >> 1) & 3)) * 8;

  f32x4 acc[4][2] = {};
  f32x2 rbA[4], rbB[4];
  bh8 rAA, rAB;

  auto issue = [&](int t, bh8& rA_, f32x2 (&rb_)[4]) {
    const int k0 = t * 32;
    rA_ = *(const bh8*)(agA + k0);
#pragma unroll
    for (int j = 0; j < 4; ++j) rb_[j] = *(const f32x2*)(w2p + (size_t)(k0 + j) * NH);
  };
  auto stage = [&](int b, bh8& rA_, f32x2 (&rb_)[4]) {
    *(bh8*)(&As[b][awo]) = rA_;
    bh4 q0, q1;
#pragma unroll
    for (int j = 0; j < 4; ++j) {
      q0[j] = (short)f2bf(rb_[j][0]); q1[j] = (short)f2bf(rb_[j][1]);
    }
    *(bh4*)(&Bs[b][bwo]) = q0;
    *(bh4*)(&Bs[b][bwo + 32]) = q1;
  };
  auto mfma_step = [&](int b) {
    bh8 af[4];
#pragma unroll
    for (int m = 0; m < 4; ++m)
      af[m] = *(const bh8*)(&As[b][(arow + m * 16) * 32 + fslA]);
#pragma unroll
    for (int nf = 0; nf < 2; ++nf) {
      bh8 bf = *(const bh8*)(&Bs[b][(nbase + nf * 16) * 32 + bsl]);
#pragma unroll
      for (int m = 0; m < 4; ++m)
        acc[m][nf] = __builtin_amdgcn_mfma_f32_16x16x32_bf16(af[m], bf, acc[m][nf], 0, 0, 0);
    }
  };

  issue(0, rAA, rbA);
  issue(1, rAB, rbB);
  stage(0, rAA, rbA);
  BARRIER();

#pragma unroll 1
  for (int u = 0; u < 32; ++u) {
    const int t0 = 2 * u;
    if (t0 + 2 < 64) issue(t0 + 2, rAA, rbA);
    mfma_step(0);
    stage(1, rAB, rbB);
    BARRIER();
    if (t0 + 3 < 64) issue(t0 + 3, rAB, rbB);
    mfma_step(1);
    if (t0 + 2 < 64) stage(0, rAA, rbA);
    BARRIER();
  }

#pragma unroll
  for (int m = 0; m < 4; ++m) {
#pragma unroll
    for (int r = 0; r < 4; ++r) {
      int trow = mt * 128 + wr * 64 + m * 16 + (l >> 4) * 4 + r;
      if (trow < te) {
        size_t base = (size_t)(off + trow) * NH + col0 + wc * 32 + (l & 15);
#pragma unroll
        for (int nf = 0; nf < 2; ++nf)
          out[base + nf * 16] = acc[m][nf][r];
      }
    }
  }
}

extern "C" void kernel_launch(void* const* d_in, const int* in_sizes, int n_in,
                              void* d_out, int out_size, void* d_ws, size_t ws_size,
                              hipStream_t stream) {
  const float* hiddens = (const float*)d_in[0];
  const float* w1 = (const float*)d_in[1];
  const float* w2 = (const float*)d_in[2];
  const float* w3 = (const float*)d_in[3];
  const int* bsz = (const int*)d_in[4];
  float* out = (float*)d_out;

  // ws: [0, 4MB) hiddens bf16 ; [4MB, 12MB) gated bf16
  unsigned short* hb = (unsigned short*)d_ws;
  unsigned short* gated = hb + (size_t)NT * NH;

  cvt_h_kernel<<<dim3(NT * NH / 8 / 256), dim3(256), 0, stream>>>(hiddens, hb);
  moe_gemm1<<<dim3(2048), dim3(512), 0, stream>>>(hb, w1, w3, bsz, gated);
  moe_gemm2<<<dim3(1024), dim3(512), 0, stream>>>(gated, w2, bsz, out);
}

// Round 5
// 133.144 us; speedup vs baseline: 1.4847x; 1.0139x over previous
//
#include <hip/hip_runtime.h>
#include <hip/hip_bf16.h>
#include <stdint.h>

// MoE experts: E=8, T=2048, H=1024, I=2048, contiguous token groups.
// up = h@w1_e ; up_r = h@w3_e ; gated = silu(up)*up_r ; out = gated@w2_e
// bf16 MFMA compute, fp32 accumulate, weights cvt'd fp32->bf16 on the fly.
//
// Round-5: dist-4 prefetch pipeline. One BK=32 K-step per phase; loads for
// tile t issue at phase t-4, are waited at phase t-1 (stage), consumed from
// LDS at phase t -> ~3 phases (~1000+ cy) issued-to-use, covering HBM
// latency. 4 named register sets (static indices), 2 LDS buffers, raw
// lgkmcnt-only barriers (no vmem drain), setprio around MFMA cluster.

#define NE 8
#define NT 2048
#define NH 1024
#define NI 2048

typedef __attribute__((ext_vector_type(8))) short bh8;      // 8 bf16
typedef __attribute__((ext_vector_type(4))) short bh4;      // 4 bf16
typedef __attribute__((ext_vector_type(4))) float f32x4;
typedef __attribute__((ext_vector_type(2))) float f32x2;
typedef __attribute__((ext_vector_type(4))) float float4v;

#define BARRIER() asm volatile("s_waitcnt lgkmcnt(0)\n\ts_barrier" ::: "memory")

static __device__ __forceinline__ unsigned short f2bf(float f) {
  __hip_bfloat16 h = __float2bfloat16(f);   // RNE
  return *reinterpret_cast<unsigned short*>(&h);
}

// ---- hiddens fp32 -> bf16 (ws) ----
__global__ __launch_bounds__(256)
void cvt_h_kernel(const float* __restrict__ x, unsigned short* __restrict__ y) {
  int i = blockIdx.x * 256 + threadIdx.x;           // one bh8 per thread
  const float4v* xv = reinterpret_cast<const float4v*>(x);
  float4v a = xv[2 * i], b = xv[2 * i + 1];
  union { bh8 v; unsigned short u[8]; } o;
  o.u[0] = f2bf(a[0]); o.u[1] = f2bf(a[1]); o.u[2] = f2bf(a[2]); o.u[3] = f2bf(a[3]);
  o.u[4] = f2bf(b[0]); o.u[5] = f2bf(b[1]); o.u[6] = f2bf(b[2]); o.u[7] = f2bf(b[3]);
  reinterpret_cast<bh8*>(y)[i] = o.v;
}

// LDS layouts (A and B): [row 128][k 32] bf16, 4 x 16B slots per row,
// slot' = slot ^ ((row>>1)&3). Fragment read = single ds_read_b128.

// ============ GEMM1: fused h@w1 / h@w3 + silu-gate -> gated bf16 ============
// BM=128 BN=128 BK=32, 8 waves (2x4), dist-4 pipeline, 32 phases.
__global__ __launch_bounds__(512, 2)
void moe_gemm1(const unsigned short* __restrict__ hb,   // [T][H] bf16
               const float* __restrict__ w1,            // [E][H][I]
               const float* __restrict__ w3,            // [E][H][I]
               const int* __restrict__ bsz,
               unsigned short* __restrict__ gated) {    // [T][I] bf16
  const int NWG = 2048;                        // nt(16) x e(8) x mt(16)
  const int wg = (blockIdx.x & 7) * (NWG >> 3) + (blockIdx.x >> 3);
  const int mt = wg & 15;                      // minor: same (nt,e) B-panel
  const int e = (wg >> 4) & 7;
  const int nt = wg >> 7;

  int off = 0;
#pragma unroll
  for (int j = 0; j < NE; ++j) { int v = bsz[j]; off += (j < e) ? v : 0; }
  const int te = bsz[e];
  if (mt * 128 >= te) return;

  const int tid = threadIdx.x;
  const int l = tid & 63, w = tid >> 6;
  const int wr = w >> 2, wc = w & 3;           // wave tile 64m x 32n

  __shared__ __align__(16) unsigned short As[2][128 * 32];
  __shared__ __align__(16) unsigned short B1s[2][128 * 32];
  __shared__ __align__(16) unsigned short B3s[2][128 * 32];

  const int row0 = off + mt * 128;
  const int col0 = nt * 128;

  // A: thread owns row tid>>2, slot tid&3 (bh8 load, swizzled ds_write)
  int gr = row0 + (tid >> 2); if (gr > NT - 1) gr = NT - 1;
  const unsigned short* agA = hb + (size_t)gr * NH + (tid & 3) * 8;
  const int awo = (tid >> 2) * 32 + (((tid & 3) ^ ((tid >> 3) & 3)) * 8);

  // B: lane owns cols 2l, 2l+1; wave w owns k-quad 4w..4w+3.
  const int n0 = 2 * l;
  const float* w1p = w1 + (size_t)e * NH * NI + (size_t)(4 * w) * NI + (col0 + n0);
  const float* w3p = w3 + (size_t)e * NH * NI + (size_t)(4 * w) * NI + (col0 + n0);
  const int bwo = n0 * 32 + (((w >> 1) ^ (l & 3)) * 8) + (w & 1) * 4;  // shorts

  const int arow = wr * 64 + (l & 15);
  const int fslA = ((l >> 4) ^ ((l >> 1) & 3)) * 8;
  const int nbase = wc * 32 + (l & 15);
  const int bsl = ((l >> 4) ^ ((nbase >> 1) & 3)) * 8;

  f32x4 acc1[4][2] = {};
  f32x4 acc3[4][2] = {};
  // 4 named prefetch sets (static indexing only)
  bh8 rA0, rA1, rA2, rA3;
  f32x2 r10[4], r11[4], r12[4], r13[4];
  f32x2 r30[4], r31[4], r32[4], r33[4];

  auto issue = [&](int t, bh8& rA_, f32x2 (&rb1_)[4], f32x2 (&rb3_)[4]) {
    const int k0 = t * 32;
    rA_ = *(const bh8*)(agA + k0);
#pragma unroll
    for (int j = 0; j < 4; ++j) rb1_[j] = *(const f32x2*)(w1p + (size_t)(k0 + j) * NI);
#pragma unroll
    for (int j = 0; j < 4; ++j) rb3_[j] = *(const f32x2*)(w3p + (size_t)(k0 + j) * NI);
  };
  auto stage = [&](int b, bh8& rA_, f32x2 (&rb1_)[4], f32x2 (&rb3_)[4]) {
    *(bh8*)(&As[b][awo]) = rA_;
    bh4 q0, q1, r0, r1;
#pragma unroll
    for (int j = 0; j < 4; ++j) {
      q0[j] = (short)f2bf(rb1_[j][0]); q1[j] = (short)f2bf(rb1_[j][1]);
      r0[j] = (short)f2bf(rb3_[j][0]); r1[j] = (short)f2bf(rb3_[j][1]);
    }
    *(bh4*)(&B1s[b][bwo]) = q0;
    *(bh4*)(&B1s[b][bwo + 32]) = q1;
    *(bh4*)(&B3s[b][bwo]) = r0;
    *(bh4*)(&B3s[b][bwo + 32]) = r1;
  };
  auto mfma_step = [&](int b) {
    bh8 af[4];
#pragma unroll
    for (int m = 0; m < 4; ++m)
      af[m] = *(const bh8*)(&As[b][(arow + m * 16) * 32 + fslA]);
    __builtin_amdgcn_s_setprio(1);
#pragma unroll
    for (int nf = 0; nf < 2; ++nf) {
      bh8 b1f = *(const bh8*)(&B1s[b][(nbase + nf * 16) * 32 + bsl]);
      bh8 b3f = *(const bh8*)(&B3s[b][(nbase + nf * 16) * 32 + bsl]);
#pragma unroll
      for (int m = 0; m < 4; ++m) {
        acc1[m][nf] = __builtin_amdgcn_mfma_f32_16x16x32_bf16(af[m], b1f, acc1[m][nf], 0, 0, 0);
        acc3[m][nf] = __builtin_amdgcn_mfma_f32_16x16x32_bf16(af[m], b3f, acc3[m][nf], 0, 0, 0);
      }
    }
    __builtin_amdgcn_s_setprio(0);
  };
  // phase p: issue tile p+4 -> setI ; mfma tile p from LDS[p&1] ;
  //          stage tile p+1 (setS, waited: issued at phase p-3) -> LDS[(p+1)&1]
#define PHASE(P, RAI, R1I, R3I, RAS, R1S, R3S, LDSP)                    \
  {                                                                     \
    if ((P) + 4 < 32) issue((P) + 4, RAI, R1I, R3I);                    \
    mfma_step(LDSP);                                                    \
    if ((P) + 1 < 32) stage((LDSP) ^ 1, RAS, R1S, R3S);                 \
    BARRIER();                                                          \
  }

  // prologue: tiles 0..3 in flight; stage tile 0 -> LDS0.
  issue(0, rA0, r10, r30);
  issue(1, rA1, r11, r31);
  issue(2, rA2, r12, r32);
  issue(3, rA3, r13, r33);
  stage(0, rA0, r10, r30);
  BARRIER();

#pragma unroll 1
  for (int p = 0; p < 32; p += 4) {
    PHASE(p + 0, rA0, r10, r30, rA1, r11, r31, 0);
    PHASE(p + 1, rA1, r11, r31, rA2, r12, r32, 1);
    PHASE(p + 2, rA2, r12, r32, rA3, r13, r33, 0);
    PHASE(p + 3, rA3, r13, r33, rA0, r10, r30, 1);
  }
#undef PHASE

  // epilogue: silu(acc1)*acc3 -> gated bf16, masked by ragged bound
#pragma unroll
  for (int m = 0; m < 4; ++m) {
#pragma unroll
    for (int r = 0; r < 4; ++r) {
      int trow = mt * 128 + wr * 64 + m * 16 + (l >> 4) * 4 + r;
      if (trow < te) {
        size_t base = (size_t)(off + trow) * NI + col0 + wc * 32 + (l & 15);
#pragma unroll
        for (int nf = 0; nf < 2; ++nf) {
          float u2 = acc1[m][nf][r];
          float g = acc3[m][nf][r];
          gated[base + nf * 16] = f2bf((u2 / (1.f + __expf(-u2))) * g);
        }
      }
    }
  }
}

// ============ GEMM2: gated @ w2 -> out fp32 ============
// BM=128 BN=128 BK=32, 8 waves, dist-4 pipeline, 64 phases.
__global__ __launch_bounds__(512, 2)
void moe_gemm2(const unsigned short* __restrict__ gated,  // [T][I] bf16
               const float* __restrict__ w2,              // [E][I][H]
               const int* __restrict__ bsz,
               float* __restrict__ out) {                 // [T][H] fp32
  const int NWG = 1024;                        // nt(8) x e(8) x mt(16)
  const int wg = (blockIdx.x & 7) * (NWG >> 3) + (blockIdx.x >> 3);
  const int mt = wg & 15;
  const int e = (wg >> 4) & 7;
  const int nt = wg >> 7;

  int off = 0;
#pragma unroll
  for (int j = 0; j < NE; ++j) { int v = bsz[j]; off += (j < e) ? v : 0; }
  const int te = bsz[e];
  if (mt * 128 >= te) return;

  const int tid = threadIdx.x;
  const int l = tid & 63, w = tid >> 6;
  const int wr = w >> 2, wc = w & 3;

  __shared__ __align__(16) unsigned short As[2][128 * 32];
  __shared__ __align__(16) unsigned short Bs[2][128 * 32];

  const int row0 = off + mt * 128;
  const int col0 = nt * 128;

  int gr = row0 + (tid >> 2); if (gr > NT - 1) gr = NT - 1;
  const unsigned short* agA = gated + (size_t)gr * NI + (tid & 3) * 8;
  const int awo = (tid >> 2) * 32 + (((tid & 3) ^ ((tid >> 3) & 3)) * 8);

  const int n0 = 2 * l;
  const float* w2p = w2 + (size_t)e * NI * NH + (size_t)(4 * w) * NH + (col0 + n0);
  const int bwo = n0 * 32 + (((w >> 1) ^ (l & 3)) * 8) + (w & 1) * 4;

  const int arow = wr * 64 + (l & 15);
  const int fslA = ((l >> 4) ^ ((l >> 1) & 3)) * 8;
  const int nbase = wc * 32 + (l & 15);
  const int bsl = ((l >> 4) ^ ((nbase >> 1) & 3)) * 8;

  f32x4 acc[4][2] = {};
  bh8 rA0, rA1, rA2, rA3;
  f32x2 r0_[4], r1_[4], r2_[4], r3_[4];

  auto issue = [&](int t, bh8& rA_, f32x2 (&rb_)[4]) {
    const int k0 = t * 32;
    rA_ = *(const bh8*)(agA + k0);
#pragma unroll
    for (int j = 0; j < 4; ++j) rb_[j] = *(const f32x2*)(w2p + (size_t)(k0 + j) * NH);
  };
  auto stage = [&](int b, bh8& rA_, f32x2 (&rb_)[4]) {
    *(bh8*)(&As[b][awo]) = rA_;
    bh4 q0, q1;
#pragma unroll
    for (int j = 0; j < 4; ++j) {
      q0[j] = (short)f2bf(rb_[j][0]); q1[j] = (short)f2bf(rb_[j][1]);
    }
    *(bh4*)(&Bs[b][bwo]) = q0;
    *(bh4*)(&Bs[b][bwo + 32]) = q1;
  };
  auto mfma_step = [&](int b) {
    bh8 af[4];
#pragma unroll
    for (int m = 0; m < 4; ++m)
      af[m] = *(const bh8*)(&As[b][(arow + m * 16) * 32 + fslA]);
    __builtin_amdgcn_s_setprio(1);
#pragma unroll
    for (int nf = 0; nf < 2; ++nf) {
      bh8 bf = *(const bh8*)(&Bs[b][(nbase + nf * 16) * 32 + bsl]);
#pragma unroll
      for (int m = 0; m < 4; ++m)
        acc[m][nf] = __builtin_amdgcn_mfma_f32_16x16x32_bf16(af[m], bf, acc[m][nf], 0, 0, 0);
    }
    __builtin_amdgcn_s_setprio(0);
  };
#define PHASE2(P, RAI, RBI, RAS, RBS, LDSP)                             \
  {                                                                     \
    if ((P) + 4 < 64) issue((P) + 4, RAI, RBI);                         \
    mfma_step(LDSP);                                                    \
    if ((P) + 1 < 64) stage((LDSP) ^ 1, RAS, RBS);                      \
    BARRIER();                                                          \
  }

  issue(0, rA0, r0_);
  issue(1, rA1, r1_);
  issue(2, rA2, r2_);
  issue(3, rA3, r3_);
  stage(0, rA0, r0_);
  BARRIER();

#pragma unroll 1
  for (int p = 0; p < 64; p += 4) {
    PHASE2(p + 0, rA0, r0_, rA1, r1_, 0);
    PHASE2(p + 1, rA1, r1_, rA2, r2_, 1);
    PHASE2(p + 2, rA2, r2_, rA3, r3_, 0);
    PHASE2(p + 3, rA3, r3_, rA0, r0_, 1);
  }
#undef PHASE2

#pragma unroll
  for (int m = 0; m < 4; ++m) {
#pragma unroll
    for (int r = 0; r < 4; ++r) {
      int trow = mt * 128 + wr * 64 + m * 16 + (l >> 4) * 4 + r;
      if (trow < te) {
        size_t base = (size_t)(off + trow) * NH + col0 + wc * 32 + (l & 15);
#pragma unroll
        for (int nf = 0; nf < 2; ++nf)
          out[base + nf * 16] = acc[m][nf][r];
      }
    }
  }
}

extern "C" void kernel_launch(void* const* d_in, const int* in_sizes, int n_in,
                              void* d_out, int out_size, void* d_ws, size_t ws_size,
                              hipStream_t stream) {
  const float* hiddens = (const float*)d_in[0];
  const float* w1 = (const float*)d_in[1];
  const float* w2 = (const float*)d_in[2];
  const float* w3 = (const float*)d_in[3];
  const int* bsz = (const int*)d_in[4];
  float* out = (float*)d_out;

  // ws: [0, 4MB) hiddens bf16 ; [4MB, 12MB) gated bf16
  unsigned short* hb = (unsigned short*)d_ws;
  unsigned short* gated = hb + (size_t)NT * NH;

  cvt_h_kernel<<<dim3(NT * NH / 8 / 256), dim3(256), 0, stream>>>(hiddens, hb);
  moe_gemm1<<<dim3(2048), dim3(512), 0, stream>>>(hb, w1, w3, bsz, gated);
  moe_gemm2<<<dim3(1024), dim3(512), 0, stream>>>(gated, w2, bsz, out);
}